// Round 3
// baseline (717.531 us; speedup 1.0000x reference)
//
#include <hip/hip_runtime.h>
#include <math.h>

#define CC 256      // channels
#define HW 65536    // 256*256 pixels
#define SS 256      // pooled spatial (16*16)

// ws layout (float offsets)
#define WS_XT   0        // Xt[s][c]  (pooled sup_x, TRANSPOSED) 256*256
#define WS_XN   65536    // Xn[c][s]                             256*256
#define WS_YG   131072   // pooled sup_y [256]
#define WS_INVN 131328   // 1/max(||Xn[:,n]||,1e-4)  [256]
#define WS_SELF 131584   // sel flag as float        [256]

// ---------------------------------------------------------------- pooling
__global__ void pool_kernel(const float* __restrict__ sup_x,
                            const float* __restrict__ sup_y,
                            float* __restrict__ ws) {
    int blk = blockIdx.x;
    int t   = threadIdx.x;
    const float* src = (blk < CC) ? (sup_x + (size_t)blk * HW) : sup_y;

    for (int py = 0; py < 16; ++py) {
        float acc = 0.f;
        int hbase = py * 16;
        #pragma unroll
        for (int i = 0; i < 16; ++i)
            acc += src[(hbase + i) * 256 + t];
        acc += __shfl_down(acc, 8, 16);
        acc += __shfl_down(acc, 4, 16);
        acc += __shfl_down(acc, 2, 16);
        acc += __shfl_down(acc, 1, 16);
        if ((t & 15) == 0) {
            int cell = py * 16 + (t >> 4);
            float v = acc * (1.f / 256.f);
            if (blk < CC) ws[WS_XT + cell * SS + blk] = v;
            else          ws[WS_YG + cell] = v;
        }
    }
}

// ---------------------------------------------------- gram + softmax + Xn
__global__ void calib_kernel(const float* __restrict__ cal,
                             float* __restrict__ ws) {
    int i = blockIdx.x;
    int j = threadIdx.x;
    const float* Xt = ws + WS_XT;
    float* Xn = ws + WS_XN;

    __shared__ float xi[SS];
    __shared__ float red[256];
    __shared__ float e[CC];
    __shared__ float T[3];

    xi[j] = Xt[j * SS + i];
    __syncthreads();

    // 4 accumulators + unroll 16 -> 16 independent loads in flight
    float d0 = 0.f, d1 = 0.f, d2 = 0.f, d3 = 0.f;
    #pragma unroll 4
    for (int s = 0; s < SS; s += 4) {
        d0 += xi[s + 0] * Xt[(s + 0) * SS + j];
        d1 += xi[s + 1] * Xt[(s + 1) * SS + j];
        d2 += xi[s + 2] * Xt[(s + 2) * SS + j];
        d3 += xi[s + 3] * Xt[(s + 3) * SS + j];
    }
    float dot = (d0 + d1) + (d2 + d3);

    red[j] = dot; __syncthreads();
    for (int off = 128; off > 0; off >>= 1) {
        if (j < off) red[j] = fmaxf(red[j], red[j + off]);
        __syncthreads();
    }
    float m = red[0];
    __syncthreads();

    float ev = expf(dot - m);
    e[j] = ev;
    red[j] = ev; __syncthreads();
    for (int off = 128; off > 0; off >>= 1) {
        if (j < off) red[j] += red[j + off];
        __syncthreads();
    }
    float esum = red[0];
    __syncthreads();

    if (j < 3) {
        int jj = i + j - 1;
        float tv = 0.f;
        if (jj >= 0 && jj < CC) {
            float soft = e[jj] / esum;
            tv = (1.f + 0.2f * soft) * cal[i * CC + jj];
        }
        T[j] = tv;
    }
    __syncthreads();

    float v = T[1] * xi[j];
    if (i > 0)      v += T[0] * Xt[j * SS + i - 1];
    if (i < CC - 1) v += T[2] * Xt[j * SS + i + 1];
    Xn[i * SS + j] = v;
}

// ------------------------------------------------ proto inv-norms + sel
// 8 blocks x 256 threads; block b covers protos b*32..b*32+31.
__global__ void prep_kernel(float* __restrict__ ws) {
    int b = blockIdx.x;
    int t = threadIdx.x;
    int nn = t & 31, cg = t >> 5;
    int n = b * 32 + nn;
    const float* Xn = ws + WS_XN;
    float s = 0.f;
    #pragma unroll 8
    for (int c = cg * 32; c < cg * 32 + 32; ++c) {
        float v = Xn[c * SS + n];
        s += v * v;
    }
    __shared__ float red[256];
    red[t] = s;
    __syncthreads();
    if (t < 32) {
        float acc = 0.f;
        #pragma unroll
        for (int g = 0; g < 8; ++g) acc += red[g * 32 + t];
        ws[WS_INVN + n] = 1.f / fmaxf(sqrtf(acc), 1e-4f);
        ws[WS_SELF + n] = (ws[WS_YG + n] > 0.5f) ? 1.f : 0.f;
    }
}

// ------------------------------------- fused GEMM + softmax + argmax
// 512 threads: 128 px x 256 protos per block. Thread (tm=tid>>5, tn=tid&31):
// 8 px (tm*8+i) x 8 protos (n = tn*4+{0..3} and 128+tn*4+{0..3}).
// K in 16-chunks, double-buffered LDS, register prefetch, 1 barrier/chunk.
#define MB 128
#define KC 16
#define NCHUNK (CC / KC)
#define BUF_F (KC * MB + KC * 256)   // 6144 floats per buffer

__global__ __launch_bounds__(512, 2)
void main_kernel(const float* __restrict__ qry,
                 const float* __restrict__ ws,
                 float* __restrict__ out) {
    __shared__ float smem[2 * BUF_F];        // 48 KB double buffer
    __shared__ float invn_s[256];
    __shared__ float self_s[256];
    __shared__ float invq_s[MB];
    __shared__ float mfin[MB];
    __shared__ float afin[MB];

    int tid = threadIdx.x;
    int tn = tid & 31;        // proto group
    int tm = tid >> 5;        // pixel group (0..15)
    int p0 = blockIdx.x * MB;
    const float* Xn = ws + WS_XN;

    if (tid < 256) {
        invn_s[tid] = ws[WS_INVN + tid];
        self_s[tid] = ws[WS_SELF + tid];
    }

    float acc[8][8];
    #pragma unroll
    for (int i = 0; i < 8; ++i)
        #pragma unroll
        for (int j = 0; j < 8; ++j) acc[i][j] = 0.f;

    // staging coords: q -> row tm, pixel-quad tn; b -> rows bk,bk+8, col-quad bc4
    int bk = tid >> 6, bc4 = tid & 63;
    float qp0 = 0.f, qp1 = 0.f, qp2 = 0.f, qp3 = 0.f;  // ||q||^2 partials (pixels 4tn..4tn+3)

    // prologue: chunk 0 -> buf0
    {
        float4 qv  = *reinterpret_cast<const float4*>(&qry[(size_t)tm * HW + p0 + tn * 4]);
        float4 bv0 = *reinterpret_cast<const float4*>(&Xn[bk * SS + bc4 * 4]);
        float4 bv1 = *reinterpret_cast<const float4*>(&Xn[(bk + 8) * SS + bc4 * 4]);
        qp0 += qv.x * qv.x; qp1 += qv.y * qv.y; qp2 += qv.z * qv.z; qp3 += qv.w * qv.w;
        *reinterpret_cast<float4*>(&smem[tm * MB + tn * 4]) = qv;
        *reinterpret_cast<float4*>(&smem[KC * MB + bk * 256 + bc4 * 4]) = bv0;
        *reinterpret_cast<float4*>(&smem[KC * MB + (bk + 8) * 256 + bc4 * 4]) = bv1;
    }
    __syncthreads();

    for (int kc = 0; kc < NCHUNK; ++kc) {
        const float* qs = smem + (kc & 1) * BUF_F;
        const float* bs = qs + KC * MB;

        float4 nqv, nbv0, nbv1;
        if (kc + 1 < NCHUNK) {
            int k0 = (kc + 1) * KC;
            nqv  = *reinterpret_cast<const float4*>(&qry[(size_t)(k0 + tm) * HW + p0 + tn * 4]);
            nbv0 = *reinterpret_cast<const float4*>(&Xn[(k0 + bk) * SS + bc4 * 4]);
            nbv1 = *reinterpret_cast<const float4*>(&Xn[(k0 + bk + 8) * SS + bc4 * 4]);
        }

        #pragma unroll
        for (int kk = 0; kk < KC; ++kk) {
            float4 qa = *reinterpret_cast<const float4*>(&qs[kk * MB + tm * 8]);
            float4 qb = *reinterpret_cast<const float4*>(&qs[kk * MB + tm * 8 + 4]);
            float4 b0 = *reinterpret_cast<const float4*>(&bs[kk * 256 + tn * 4]);
            float4 b1 = *reinterpret_cast<const float4*>(&bs[kk * 256 + tn * 4 + 128]);
            float q8[8] = {qa.x, qa.y, qa.z, qa.w, qb.x, qb.y, qb.z, qb.w};
            float b8[8] = {b0.x, b0.y, b0.z, b0.w, b1.x, b1.y, b1.z, b1.w};
            #pragma unroll
            for (int i = 0; i < 8; ++i)
                #pragma unroll
                for (int j = 0; j < 8; ++j)
                    acc[i][j] += q8[i] * b8[j];
        }

        if (kc + 1 < NCHUNK) {
            qp0 += nqv.x * nqv.x; qp1 += nqv.y * nqv.y;
            qp2 += nqv.z * nqv.z; qp3 += nqv.w * nqv.w;
            float* qs1 = smem + ((kc + 1) & 1) * BUF_F;
            *reinterpret_cast<float4*>(&qs1[tm * MB + tn * 4]) = nqv;
            *reinterpret_cast<float4*>(&qs1[KC * MB + bk * 256 + bc4 * 4]) = nbv0;
            *reinterpret_cast<float4*>(&qs1[KC * MB + (bk + 8) * 256 + bc4 * 4]) = nbv1;
        }
        __syncthreads();
    }

    // ---- per-pixel ||q||^2: thread (tm,tn) holds partials for pixels 4tn..4tn+3
    {
        float4 qp = {qp0, qp1, qp2, qp3};
        reinterpret_cast<float4*>(smem)[tid] = qp;    // qred4[tid]
    }
    __syncthreads();
    if (tid < MB) {
        int p4 = tid >> 2, e = tid & 3;
        float s = 0.f;
        #pragma unroll
        for (int kk = 0; kk < 16; ++kk)
            s += smem[(kk * 32 + p4) * 4 + e];
        invq_s[tid] = 1.f / fmaxf(sqrtf(s), 1e-4f);
    }
    __syncthreads();

    // ---- phase A: scale+mask in-register, thread-local max/argmax
    float* rmax = smem;          // [128][33]
    float* rarg = smem + 4224;   // [128][33]
    #pragma unroll
    for (int i = 0; i < 8; ++i) {
        int p = tm * 8 + i;
        float iq = invq_s[p] * 20.f;
        float bv = -3.4e38f;
        int   ba = 0;
        #pragma unroll
        for (int j = 0; j < 8; ++j) {
            int n = (j < 4) ? (tn * 4 + j) : (tn * 4 + 124 + j);  // ascending
            float d = acc[i][j] * invn_s[n] * iq;
            d = (self_s[n] > 0.5f) ? d : -1e9f;
            acc[i][j] = d;
            if (d > bv) { bv = d; ba = n; }
        }
        rmax[p * 33 + tn] = bv;
        rarg[p * 33 + tn] = (float)ba;
    }
    __syncthreads();

    // reduce 32 partials/pixel: 4 threads per pixel + shfl over width 4
    {
        int p = tid >> 2, q4 = tid & 3;
        float bv = -3.4e38f, ba = 1e9f;
        #pragma unroll
        for (int jj = 0; jj < 8; ++jj) {
            int t2 = q4 * 8 + jj;
            float v = rmax[p * 33 + t2];
            float a = rarg[p * 33 + t2];
            if (v > bv || (v == bv && a < ba)) { bv = v; ba = a; }
        }
        #pragma unroll
        for (int off = 1; off < 4; off <<= 1) {
            float ov = __shfl_xor(bv, off, 4);
            float oa = __shfl_xor(ba, off, 4);
            if (ov > bv || (ov == bv && oa < ba)) { bv = ov; ba = oa; }
        }
        if (q4 == 0) { mfin[p] = bv; afin[p] = ba; }
    }
    __syncthreads();

    // ---- phase B: exp-sums from registers
    float* s1a = smem;           // [128][33]
    float* s2a = smem + 4224;
    #pragma unroll
    for (int i = 0; i < 8; ++i) {
        int p = tm * 8 + i;
        float m = mfin[p];
        float s1 = 0.f, s2 = 0.f;
        #pragma unroll
        for (int j = 0; j < 8; ++j) {
            float v = acc[i][j];
            float ev = expf(v - m);
            s1 += ev;
            s2 += ev * v;
        }
        s1a[p * 33 + tn] = s1;
        s2a[p * 33 + tn] = s2;
    }
    __syncthreads();

    {
        int p = tid >> 2, q4 = tid & 3;
        float s1 = 0.f, s2 = 0.f;
        #pragma unroll
        for (int jj = 0; jj < 8; ++jj) {
            int t2 = q4 * 8 + jj;
            s1 += s1a[p * 33 + t2];
            s2 += s2a[p * 33 + t2];
        }
        #pragma unroll
        for (int off = 1; off < 4; off <<= 1) {
            s1 += __shfl_xor(s1, off, 4);
            s2 += __shfl_xor(s2, off, 4);
        }
        if (q4 == 0) {
            out[p0 + p]      = s2 / s1;    // pred_grid
            out[HW + p0 + p] = afin[p];    // debug_assign
        }
    }
}

// ----------------------------------------------------------------- launch
extern "C" void kernel_launch(void* const* d_in, const int* in_sizes, int n_in,
                              void* d_out, int out_size, void* d_ws, size_t ws_size,
                              hipStream_t stream) {
    const float* qry   = (const float*)d_in[0];
    const float* sup_x = (const float*)d_in[1];
    const float* sup_y = (const float*)d_in[2];
    // d_in[3] = s_init_seed (unused by reference)
    const float* cal   = (const float*)d_in[4];
    float* out = (float*)d_out;
    float* ws  = (float*)d_ws;

    pool_kernel<<<257, 256, 0, stream>>>(sup_x, sup_y, ws);
    calib_kernel<<<256, 256, 0, stream>>>(cal, ws);
    prep_kernel<<<8, 256, 0, stream>>>(ws);
    main_kernel<<<HW / MB, 512, 0, stream>>>(qry, ws, out);
}

// Round 4
// 276.151 us; speedup vs baseline: 2.5983x; 2.5983x over previous
//
#include <hip/hip_runtime.h>
#include <math.h>

#define CC 256      // channels
#define HW 65536    // 256*256 pixels
#define SS 256      // pooled spatial (16*16)

// ws layout (float offsets)
#define WS_XT   0        // Xt[s][c]  (pooled sup_x, TRANSPOSED) 256*256
#define WS_XN   65536    // Xn[c][s]                             256*256
#define WS_YG   131072   // pooled sup_y [256]
#define WS_INVN 131328   // 1/max(||Xn[:,n]||,1e-4)  [256]
#define WS_SELF 131584   // sel flag as float        [256]

// ---------------------------------------------------------------- pooling
__global__ void pool_kernel(const float* __restrict__ sup_x,
                            const float* __restrict__ sup_y,
                            float* __restrict__ ws) {
    int blk = blockIdx.x;
    int t   = threadIdx.x;
    const float* src = (blk < CC) ? (sup_x + (size_t)blk * HW) : sup_y;

    for (int py = 0; py < 16; ++py) {
        float acc = 0.f;
        int hbase = py * 16;
        #pragma unroll
        for (int i = 0; i < 16; ++i)
            acc += src[(hbase + i) * 256 + t];
        acc += __shfl_down(acc, 8, 16);
        acc += __shfl_down(acc, 4, 16);
        acc += __shfl_down(acc, 2, 16);
        acc += __shfl_down(acc, 1, 16);
        if ((t & 15) == 0) {
            int cell = py * 16 + (t >> 4);
            float v = acc * (1.f / 256.f);
            if (blk < CC) ws[WS_XT + cell * SS + blk] = v;
            else          ws[WS_YG + cell] = v;
        }
    }
}

// ---------------------------------------------------- gram + softmax + Xn
__global__ void calib_kernel(const float* __restrict__ cal,
                             float* __restrict__ ws) {
    int i = blockIdx.x;
    int j = threadIdx.x;
    const float* Xt = ws + WS_XT;
    float* Xn = ws + WS_XN;

    __shared__ float xi[SS];
    __shared__ float red[256];
    __shared__ float e[CC];
    __shared__ float T[3];

    xi[j] = Xt[j * SS + i];
    __syncthreads();

    float d0 = 0.f, d1 = 0.f, d2 = 0.f, d3 = 0.f;
    #pragma unroll 4
    for (int s = 0; s < SS; s += 4) {
        d0 += xi[s + 0] * Xt[(s + 0) * SS + j];
        d1 += xi[s + 1] * Xt[(s + 1) * SS + j];
        d2 += xi[s + 2] * Xt[(s + 2) * SS + j];
        d3 += xi[s + 3] * Xt[(s + 3) * SS + j];
    }
    float dot = (d0 + d1) + (d2 + d3);

    red[j] = dot; __syncthreads();
    for (int off = 128; off > 0; off >>= 1) {
        if (j < off) red[j] = fmaxf(red[j], red[j + off]);
        __syncthreads();
    }
    float m = red[0];
    __syncthreads();

    float ev = expf(dot - m);
    e[j] = ev;
    red[j] = ev; __syncthreads();
    for (int off = 128; off > 0; off >>= 1) {
        if (j < off) red[j] += red[j + off];
        __syncthreads();
    }
    float esum = red[0];
    __syncthreads();

    if (j < 3) {
        int jj = i + j - 1;
        float tv = 0.f;
        if (jj >= 0 && jj < CC) {
            float soft = e[jj] / esum;
            tv = (1.f + 0.2f * soft) * cal[i * CC + jj];
        }
        T[j] = tv;
    }
    __syncthreads();

    float v = T[1] * xi[j];
    if (i > 0)      v += T[0] * Xt[j * SS + i - 1];
    if (i < CC - 1) v += T[2] * Xt[j * SS + i + 1];
    Xn[i * SS + j] = v;
}

// ------------------------------------------------ proto inv-norms + sel
__global__ void prep_kernel(float* __restrict__ ws) {
    int b = blockIdx.x;
    int t = threadIdx.x;
    int nn = t & 31, cg = t >> 5;
    int n = b * 32 + nn;
    const float* Xn = ws + WS_XN;
    float s = 0.f;
    #pragma unroll 8
    for (int c = cg * 32; c < cg * 32 + 32; ++c) {
        float v = Xn[c * SS + n];
        s += v * v;
    }
    __shared__ float red[256];
    red[t] = s;
    __syncthreads();
    if (t < 32) {
        float acc = 0.f;
        #pragma unroll
        for (int g = 0; g < 8; ++g) acc += red[g * 32 + t];
        ws[WS_INVN + n] = 1.f / fmaxf(sqrtf(acc), 1e-4f);
        ws[WS_SELF + n] = (ws[WS_YG + n] > 0.5f) ? 1.f : 0.f;
    }
}

// ------------------------------------- fused GEMM + softmax + argmax
// R1's proven no-spill core: 256 threads, 64 px x 256 protos, acc[8][8],
// single-buffer LDS, 2 barriers/chunk. Epilogue fully in-register (no dt
// tile) with small partial buffers reusing the staging LDS.
#define MB 64
#define KC 16

__global__ __launch_bounds__(256, 2)
void main_kernel(const float* __restrict__ qry,
                 const float* __restrict__ ws,
                 float* __restrict__ out) {
    __shared__ float smem[KC * MB + KC * 256];   // qs[16][64] | bs[16][256] = 5120 floats
    __shared__ float invn_s[256];
    __shared__ float self_s[256];
    __shared__ float invq_s[MB];
    __shared__ float mfin[MB];
    __shared__ float afin[MB];

    int tid = threadIdx.x;
    int tm = tid & 7;         // pixel group: px tm*8+i
    int tn = tid >> 3;        // proto group: n = tn*8+j (0..31)
    int p0 = blockIdx.x * MB;
    const float* Xn = ws + WS_XN;
    float* qs = smem;               // [KC][64]
    float* bs = smem + KC * MB;     // [KC][256]

    invn_s[tid] = ws[WS_INVN + tid];
    self_s[tid] = ws[WS_SELF + tid];

    float acc[8][8];
    #pragma unroll
    for (int i = 0; i < 8; ++i)
        #pragma unroll
        for (int j = 0; j < 8; ++j) acc[i][j] = 0.f;

    // staging coords (float4 both sides)
    int qr = tid >> 4, qc4 = tid & 15;    // q: row qr, pixel-quad qc4
    int br = tid >> 6, bc4 = tid & 63;    // b: rows br,br+4,br+8,br+12, col-quad bc4
    float qp0 = 0.f, qp1 = 0.f, qp2 = 0.f, qp3 = 0.f;  // ||q||^2 partials, pixels qc4*4..+3

    for (int k0 = 0; k0 < CC; k0 += KC) {
        __syncthreads();
        {
            float4 qv = *reinterpret_cast<const float4*>(
                &qry[(size_t)(k0 + qr) * HW + p0 + qc4 * 4]);
            qp0 += qv.x * qv.x; qp1 += qv.y * qv.y;
            qp2 += qv.z * qv.z; qp3 += qv.w * qv.w;
            *reinterpret_cast<float4*>(&qs[qr * MB + qc4 * 4]) = qv;
            #pragma unroll
            for (int u = 0; u < 4; ++u) {
                float4 bv = *reinterpret_cast<const float4*>(
                    &Xn[(k0 + br + 4 * u) * SS + bc4 * 4]);
                *reinterpret_cast<float4*>(&bs[(br + 4 * u) * 256 + bc4 * 4]) = bv;
            }
        }
        __syncthreads();

        #pragma unroll
        for (int kk = 0; kk < KC; ++kk) {
            float4 qa = *reinterpret_cast<const float4*>(&qs[kk * MB + tm * 8]);
            float4 qb = *reinterpret_cast<const float4*>(&qs[kk * MB + tm * 8 + 4]);
            float4 ba = *reinterpret_cast<const float4*>(&bs[kk * 256 + tn * 8]);
            float4 bb = *reinterpret_cast<const float4*>(&bs[kk * 256 + tn * 8 + 4]);
            float q8[8] = {qa.x, qa.y, qa.z, qa.w, qb.x, qb.y, qb.z, qb.w};
            float b8[8] = {ba.x, ba.y, ba.z, ba.w, bb.x, bb.y, bb.z, bb.w};
            #pragma unroll
            for (int i = 0; i < 8; ++i)
                #pragma unroll
                for (int j = 0; j < 8; ++j)
                    acc[i][j] += q8[i] * b8[j];
        }
    }
    __syncthreads();   // protect smem before reuse

    // ---- per-pixel ||q||^2: thread (qr,qc4) holds partials for pixels qc4*4..+3
    {
        float4 qp = {qp0, qp1, qp2, qp3};
        reinterpret_cast<float4*>(smem)[tid] = qp;
    }
    __syncthreads();
    if (tid < MB) {
        int c4 = tid >> 2, e = tid & 3;
        float s = 0.f;
        #pragma unroll
        for (int r = 0; r < 16; ++r)
            s += smem[(r * 16 + c4) * 4 + e];
        invq_s[tid] = 1.f / fmaxf(sqrtf(s), 1e-4f);
    }
    __syncthreads();

    // ---- phase A: scale+mask in-register, thread-local max/argmax
    float* rmax = smem;          // [64][33]
    float* rarg = smem + 2112;   // [64][33]
    #pragma unroll
    for (int i = 0; i < 8; ++i) {
        int p = tm * 8 + i;
        float iq = invq_s[p] * 20.f;
        float bv = -3.4e38f;
        int   ba = 0;
        #pragma unroll
        for (int j = 0; j < 8; ++j) {
            int n = tn * 8 + j;                     // ascending in j
            float d = acc[i][j] * invn_s[n] * iq;
            d = (self_s[n] > 0.5f) ? d : -1e9f;
            acc[i][j] = d;
            if (d > bv) { bv = d; ba = n; }         // strict > keeps lowest n
        }
        rmax[p * 33 + tn] = bv;
        rarg[p * 33 + tn] = (float)ba;
    }
    __syncthreads();

    // reduce 32 partials/pixel: 4 threads per pixel + shfl over width 4
    {
        int p = tid >> 2, q4 = tid & 3;
        float bv = -3.4e38f, ba = 1e9f;
        #pragma unroll
        for (int jj = 0; jj < 8; ++jj) {
            int t2 = q4 * 8 + jj;
            float v = rmax[p * 33 + t2];
            float a = rarg[p * 33 + t2];
            if (v > bv || (v == bv && a < ba)) { bv = v; ba = a; }
        }
        #pragma unroll
        for (int off = 1; off < 4; off <<= 1) {
            float ov = __shfl_xor(bv, off, 4);
            float oa = __shfl_xor(ba, off, 4);
            if (ov > bv || (ov == bv && oa < ba)) { bv = ov; ba = oa; }
        }
        if (q4 == 0) { mfin[p] = bv; afin[p] = ba; }
    }
    __syncthreads();

    // ---- phase B: exp-sums from registers
    float* s1a = smem;           // [64][33]
    float* s2a = smem + 2112;
    #pragma unroll
    for (int i = 0; i < 8; ++i) {
        int p = tm * 8 + i;
        float m = mfin[p];
        float s1 = 0.f, s2 = 0.f;
        #pragma unroll
        for (int j = 0; j < 8; ++j) {
            float v = acc[i][j];
            float ev = expf(v - m);    // masked -1e9 -> 0
            s1 += ev;
            s2 += ev * v;
        }
        s1a[p * 33 + tn] = s1;
        s2a[p * 33 + tn] = s2;
    }
    __syncthreads();

    {
        int p = tid >> 2, q4 = tid & 3;
        float s1 = 0.f, s2 = 0.f;
        #pragma unroll
        for (int jj = 0; jj < 8; ++jj) {
            int t2 = q4 * 8 + jj;
            s1 += s1a[p * 33 + t2];
            s2 += s2a[p * 33 + t2];
        }
        #pragma unroll
        for (int off = 1; off < 4; off <<= 1) {
            s1 += __shfl_xor(s1, off, 4);
            s2 += __shfl_xor(s2, off, 4);
        }
        if (q4 == 0) {
            out[p0 + p]      = s2 / s1;    // pred_grid
            out[HW + p0 + p] = afin[p];    // debug_assign
        }
    }
}

// ----------------------------------------------------------------- launch
extern "C" void kernel_launch(void* const* d_in, const int* in_sizes, int n_in,
                              void* d_out, int out_size, void* d_ws, size_t ws_size,
                              hipStream_t stream) {
    const float* qry   = (const float*)d_in[0];
    const float* sup_x = (const float*)d_in[1];
    const float* sup_y = (const float*)d_in[2];
    // d_in[3] = s_init_seed (unused by reference)
    const float* cal   = (const float*)d_in[4];
    float* out = (float*)d_out;
    float* ws  = (float*)d_ws;

    pool_kernel<<<257, 256, 0, stream>>>(sup_x, sup_y, ws);
    calib_kernel<<<256, 256, 0, stream>>>(cal, ws);
    prep_kernel<<<8, 256, 0, stream>>>(ws);
    main_kernel<<<HW / MB, 256, 0, stream>>>(qry, ws, out);
}